// Round 2
// baseline (1466.777 us; speedup 1.0000x reference)
//
#include <hip/hip_runtime.h>
#include <math.h>

#define EMB 32
#define NFEAT 128

__device__ __forceinline__ float lrelu(float z) { return z > 0.f ? z : 0.01f * z; }

// ---------------------------------------------------------------------------
// Embed: x = lrelu(nf @ W_embed + b_embed); m = lrelu(x @ W_msg + b_msg)
// 32 lanes per node (lane e = output channel e). Node row staged in LDS.
// ---------------------------------------------------------------------------
__global__ __launch_bounds__(256) void k_embed(
    const float* __restrict__ nf, const float* __restrict__ Wemb,
    const float* __restrict__ bemb, const float* __restrict__ Wmsg,
    const float* __restrict__ bmsg, float* __restrict__ x,
    float* __restrict__ m, int n)
{
    __shared__ float sW[NFEAT * EMB];   // 16 KB; read as sW[k*32+e]: bank==e, conflict-free
    __shared__ float sWm[EMB * EMB];    // 4 KB
    __shared__ float srow[8][NFEAT];    // 4 KB; srow[g][k] is a 32-lane broadcast read
    int t = threadIdx.x;
    for (int i = t; i < NFEAT * EMB; i += 256) sW[i] = Wemb[i];
    for (int i = t; i < EMB * EMB; i += 256) sWm[i] = Wmsg[i];
    __syncthreads();

    int g = t >> 5;       // node slot in block: 0..7
    int e = t & 31;       // embedding channel
    float be = bemb[e];
    float bm = bmsg[e];

    int per_pass = gridDim.x * 8;
    int iters = (n + per_pass - 1) / per_pass;
    for (int it = 0; it < iters; ++it) {
        int node = (it * gridDim.x + blockIdx.x) * 8 + g;
        __syncthreads();  // protect srow reuse across passes
        if (node < n) {
            // cooperative row load: 32 lanes x float4 = 128 floats (one 512B row)
            float4 v = ((const float4*)(nf + (size_t)node * NFEAT))[e];
            ((float4*)&srow[g][0])[e] = v;
        }
        __syncthreads();
        if (node < n) {
            float acc = be;
            #pragma unroll
            for (int k = 0; k < NFEAT; ++k)
                acc = fmaf(srow[g][k], sW[k * EMB + e], acc);
            float xv = lrelu(acc);
            x[(size_t)node * EMB + e] = xv;
            // fused message MLP via intra-group shuffle broadcast
            float macc = bm;
            #pragma unroll
            for (int k = 0; k < EMB; ++k)
                macc = fmaf(__shfl(xv, k, 32), sWm[k * EMB + e], macc);
            m[(size_t)node * EMB + e] = lrelu(macc);
        }
    }
}

// ---------------------------------------------------------------------------
// CSR build: histogram -> exclusive scan -> fill (src list bucketed by dst)
// ---------------------------------------------------------------------------
__global__ void k_hist(const int* __restrict__ dst, int* __restrict__ deg, int E)
{
    int i = blockIdx.x * blockDim.x + threadIdx.x;
    if (i < E) atomicAdd(&deg[dst[i]], 1);
}

__global__ void k_scan1(const int* __restrict__ deg, int* __restrict__ out,
                        int* __restrict__ partials, int n)
{
    __shared__ int sdat[256];
    int b = blockIdx.x;
    int base = b * 1024;
    int t = threadIdx.x;
    int v[4];
    int s = 0;
    #pragma unroll
    for (int j = 0; j < 4; ++j) {
        int idx = base + t * 4 + j;
        v[j] = (idx < n) ? deg[idx] : 0;
        s += v[j];
    }
    sdat[t] = s;
    __syncthreads();
    for (int off = 1; off < 256; off <<= 1) {  // Hillis-Steele inclusive
        int add = (t >= off) ? sdat[t - off] : 0;
        __syncthreads();
        sdat[t] += add;
        __syncthreads();
    }
    int run = (t > 0) ? sdat[t - 1] : 0;   // exclusive prefix of this thread
    if (t == 255) partials[b] = sdat[255];
    #pragma unroll
    for (int j = 0; j < 4; ++j) {
        int idx = base + t * 4 + j;
        if (idx < n) out[idx] = run;
        run += v[j];
    }
}

__global__ void k_scan2(int* __restrict__ partials, int nb)
{
    __shared__ int s[1024];
    int t = threadIdx.x;
    s[t] = (t < nb) ? partials[t] : 0;
    __syncthreads();
    for (int off = 1; off < 1024; off <<= 1) {
        int add = (t >= off) ? s[t - off] : 0;
        __syncthreads();
        s[t] += add;
        __syncthreads();
    }
    int excl = (t > 0) ? s[t - 1] : 0;
    if (t < nb) partials[t] = excl;
}

__global__ void k_scan3(int* __restrict__ out, int* __restrict__ cur,
                        const int* __restrict__ partials, int n)
{
    int i = blockIdx.x * blockDim.x + threadIdx.x;
    if (i < n) {
        int v = out[i] + partials[i >> 10];
        out[i] = v;
        cur[i] = v;
    }
}

__global__ void k_fill(const int* __restrict__ src, const int* __restrict__ dst,
                       int* __restrict__ cursor, int* __restrict__ csr_src, int E)
{
    int i = blockIdx.x * blockDim.x + threadIdx.x;
    if (i < E) {
        int d = dst[i];
        int pos = atomicAdd(&cursor[d], 1);
        csr_src[pos] = src[i];
    }
}

// ---------------------------------------------------------------------------
// Fused message-passing iteration:
//   agg_i = sum_{j in nbrs(i)} m_in[j]                    (CSR gather-sum)
//   x_i   = lrelu([x_i, agg_i] @ W_upd + b_upd)           (in place)
//   m_out_i = lrelu(x_i @ W_msg + b_msg)                  (if do_msg)
//   colsum += x_i                                          (if do_colsum, last iter)
// Ping-pong m buffers make this race-free: m_in is never written here.
// 32 lanes per node; 4-edge batching for memory-level parallelism.
// ---------------------------------------------------------------------------
__global__ __launch_bounds__(256) void k_mp(
    const float* __restrict__ m_in, float* __restrict__ m_out,
    float* __restrict__ x,
    const int* __restrict__ row_start, const int* __restrict__ deg,
    const int* __restrict__ csr_src,
    const float* __restrict__ Wupd, const float* __restrict__ bupd,
    const float* __restrict__ Wmsg, const float* __restrict__ bmsg,
    float* __restrict__ sums, int n, int do_msg, int do_colsum)
{
    __shared__ float sW[2 * EMB * EMB];  // 8 KB
    __shared__ float sWm[EMB * EMB];     // 4 KB
    __shared__ float red[8][EMB];        // 1 KB (colsum reduction)
    int t = threadIdx.x;
    for (int i = t; i < 2 * EMB * EMB; i += 256) sW[i] = Wupd[i];
    for (int i = t; i < EMB * EMB; i += 256) sWm[i] = Wmsg[i];
    __syncthreads();

    int g = t >> 5;
    int e = t & 31;
    float bu = bupd[e];
    float bm = bmsg[e];
    float colacc = 0.f;
    int groups = gridDim.x * 8;
    for (int node = blockIdx.x * 8 + g; node < n; node += groups) {
        int s = row_start[node];
        int d = deg[node];
        // ---- aggregate (random 128B row gather from cache-resident m_in) ----
        float acc = 0.f;
        int j = 0;
        for (; j + 4 <= d; j += 4) {
            int s0 = csr_src[s + j];
            int s1 = csr_src[s + j + 1];
            int s2 = csr_src[s + j + 2];
            int s3 = csr_src[s + j + 3];
            float a0 = m_in[(size_t)s0 * EMB + e];
            float a1 = m_in[(size_t)s1 * EMB + e];
            float a2 = m_in[(size_t)s2 * EMB + e];
            float a3 = m_in[(size_t)s3 * EMB + e];
            acc += (a0 + a1) + (a2 + a3);
        }
        for (; j < d; ++j) {
            int sj = csr_src[s + j];
            acc += m_in[(size_t)sj * EMB + e];
        }
        // ---- update GEMM via intra-group shuffle broadcast ----
        float xv = x[(size_t)node * EMB + e];
        float u = bu;
        #pragma unroll
        for (int k = 0; k < EMB; ++k)
            u = fmaf(__shfl(xv, k, 32), sW[k * EMB + e], u);
        #pragma unroll
        for (int k = 0; k < EMB; ++k)
            u = fmaf(__shfl(acc, k, 32), sW[(EMB + k) * EMB + e], u);
        float xn = lrelu(u);
        x[(size_t)node * EMB + e] = xn;
        // ---- next-iteration message ----
        if (do_msg) {
            float macc = bm;
            #pragma unroll
            for (int k = 0; k < EMB; ++k)
                macc = fmaf(__shfl(xn, k, 32), sWm[k * EMB + e], macc);
            m_out[(size_t)node * EMB + e] = lrelu(macc);
        }
        if (do_colsum) colacc += xn;
    }
    if (do_colsum) {
        red[g][e] = colacc;
        __syncthreads();
        if (t < EMB) {
            float s2 = 0.f;
            #pragma unroll
            for (int gg = 0; gg < 8; ++gg) s2 += red[gg][t];
            atomicAdd(&sums[t], s2);
        }
    }
}

// ---------------------------------------------------------------------------
// Head: value = mean(x) @ W_val + b_val; probs = softmax(x[act] @ W_pol + b_pol)
// Single block, A (=1024) threads.
// ---------------------------------------------------------------------------
__global__ __launch_bounds__(1024) void k_head(
    const float* __restrict__ x, const int* __restrict__ act,
    const float* __restrict__ Wval, const float* __restrict__ bval,
    const float* __restrict__ Wpol, const float* __restrict__ bpol,
    const float* __restrict__ sums, float* __restrict__ out, int n, int A)
{
    __shared__ float sred[64];
    int t = threadIdx.x;
    int w = t >> 6;
    int lane = t & 63;
    int nwaves = (blockDim.x + 63) >> 6;

    float logit = -INFINITY;
    if (t < A) {
        int node = act[t];
        float acc = bpol[0];
        #pragma unroll
        for (int k = 0; k < EMB; ++k)
            acc = fmaf(x[(size_t)node * EMB + k], Wpol[k], acc);
        logit = acc;
    }
    // block max
    float wm = logit;
    for (int off = 32; off; off >>= 1) wm = fmaxf(wm, __shfl_xor(wm, off, 64));
    if (lane == 0) sred[w] = wm;
    __syncthreads();
    if (t == 0) {
        float mm = -INFINITY;
        for (int i = 0; i < nwaves; ++i) mm = fmaxf(mm, sred[i]);
        sred[32] = mm;
    }
    __syncthreads();
    float bmax = sred[32];
    float ex = (t < A) ? __expf(logit - bmax) : 0.f;
    // block sum
    float ws = ex;
    for (int off = 32; off; off >>= 1) ws += __shfl_xor(ws, off, 64);
    if (lane == 0) sred[w] = ws;
    __syncthreads();
    if (t == 0) {
        float ss = 0.f;
        for (int i = 0; i < nwaves; ++i) ss += sred[i];
        sred[33] = ss;
        // value head
        float val = bval[0];
        float inv_n = 1.f / (float)n;
        #pragma unroll
        for (int k = 0; k < EMB; ++k) val = fmaf(sums[k] * inv_n, Wval[k], val);
        out[0] = val;
    }
    __syncthreads();
    float tot = sred[33];
    if (t < A) out[1 + t] = ex / tot;
}

// ---------------------------------------------------------------------------
extern "C" void kernel_launch(void* const* d_in, const int* in_sizes, int n_in,
                              void* d_out, int out_size, void* d_ws, size_t ws_size,
                              hipStream_t stream)
{
    const float* nf   = (const float*)d_in[0];
    const int*   ei   = (const int*)d_in[1];    // int per harness convention
    const int*   act  = (const int*)d_in[2];
    const float* Wemb = (const float*)d_in[3];
    const float* bemb = (const float*)d_in[4];
    const float* Wmsg = (const float*)d_in[5];
    const float* bmsg = (const float*)d_in[6];
    const float* Wupd = (const float*)d_in[7];
    const float* bupd = (const float*)d_in[8];
    const float* Wval = (const float*)d_in[9];
    const float* bval = (const float*)d_in[10];
    const float* Wpol = (const float*)d_in[11];
    const float* bpol = (const float*)d_in[12];

    int n = in_sizes[0] / NFEAT;
    int E = in_sizes[1] / 2;
    int A = in_sizes[2];
    const int* src = ei;
    const int* dst = ei + E;

    // workspace carve-out (256B aligned): ~52.6 MB total
    char* w = (char*)d_ws;
    auto alloc = [&](size_t bytes) -> void* {
        void* p = (void*)w;
        w += (bytes + 255) & ~(size_t)255;
        return p;
    };
    float* x    = (float*)alloc((size_t)n * EMB * 4);
    float* mA   = (float*)alloc((size_t)n * EMB * 4);
    float* mB   = (float*)alloc((size_t)n * EMB * 4);
    int*   deg  = (int*)alloc((size_t)n * 4);
    int*   row  = (int*)alloc((size_t)n * 4);
    int*   cur  = (int*)alloc((size_t)n * 4);
    int nb_scan = (n + 1023) / 1024;           // <= 1024 for n <= 1M
    int* partials = (int*)alloc((size_t)nb_scan * 4);
    int*   csr  = (int*)alloc((size_t)E * 4);
    float* sums = (float*)alloc(EMB * 4);

    hipMemsetAsync(deg, 0, (size_t)n * 4, stream);
    hipMemsetAsync(sums, 0, EMB * 4, stream);

    const int NB = 2048;  // 256 CU x 8 wg worth of waves; grid-stride inside

    // embed (+ first message pass)
    k_embed<<<NB, 256, 0, stream>>>(nf, Wemb, bemb, Wmsg, bmsg, x, mA, n);

    // CSR build by destination
    k_hist<<<(E + 255) / 256, 256, 0, stream>>>(dst, deg, E);
    k_scan1<<<nb_scan, 256, 0, stream>>>(deg, row, partials, n);
    k_scan2<<<1, 1024, 0, stream>>>(partials, nb_scan);
    k_scan3<<<(n + 255) / 256, 256, 0, stream>>>(row, cur, partials, n);
    k_fill<<<(E + 255) / 256, 256, 0, stream>>>(src, dst, cur, csr, E);

    // 5 fused message-passing iterations (ping-pong message buffers)
    float* mi = mA;
    float* mo = mB;
    for (int it = 0; it < 5; ++it) {
        int last = (it == 4);
        k_mp<<<NB, 256, 0, stream>>>(mi, mo, x, row, deg, csr,
                                     Wupd, bupd, Wmsg, bmsg,
                                     sums, n, last ? 0 : 1, last ? 1 : 0);
        float* tmp = mi; mi = mo; mo = tmp;
    }

    // heads
    k_head<<<1, 1024, 0, stream>>>(x, act, Wval, bval, Wpol, bpol, sums,
                                   (float*)d_out, n, A);
}

// Round 3
// 1063.517 us; speedup vs baseline: 1.3792x; 1.3792x over previous
//
#include <hip/hip_runtime.h>
#include <math.h>

#define EMB 32
#define NFEAT 128
#define RANGE 256            // nodes per bucket (dst >> 8)
#define NBUCK_MAX 512        // supports n <= 131072 (fits src in 17 bits too)
#define FILL_TILE 4096       // edges per k_bfill block (16 per thread)
#define FIN_CAP 12288        // max edges per bucket staged in LDS (48 KB)

__device__ __forceinline__ float lrelu(float z) { return z > 0.f ? z : 0.01f * z; }

// ---------------------------------------------------------------------------
// Embed: x = lrelu(nf @ W_embed + b_embed); m = lrelu(x @ W_msg + b_msg)
// ---------------------------------------------------------------------------
__global__ __launch_bounds__(256) void k_embed(
    const float* __restrict__ nf, const float* __restrict__ Wemb,
    const float* __restrict__ bemb, const float* __restrict__ Wmsg,
    const float* __restrict__ bmsg, float* __restrict__ x,
    float* __restrict__ m, int n)
{
    __shared__ float sW[NFEAT * EMB];   // 16 KB; sW[k*32+e]: bank==e, conflict-free
    __shared__ float sWm[EMB * EMB];    // 4 KB
    __shared__ float srow[8][NFEAT];    // 4 KB; srow[g][k] broadcast within group
    int t = threadIdx.x;
    for (int i = t; i < NFEAT * EMB; i += 256) sW[i] = Wemb[i];
    for (int i = t; i < EMB * EMB; i += 256) sWm[i] = Wmsg[i];
    __syncthreads();

    int g = t >> 5;
    int e = t & 31;
    float be = bemb[e];
    float bm = bmsg[e];

    int per_pass = gridDim.x * 8;
    int iters = (n + per_pass - 1) / per_pass;
    for (int it = 0; it < iters; ++it) {
        int node = (it * gridDim.x + blockIdx.x) * 8 + g;
        __syncthreads();
        if (node < n) {
            float4 v = ((const float4*)(nf + (size_t)node * NFEAT))[e];
            ((float4*)&srow[g][0])[e] = v;
        }
        __syncthreads();
        if (node < n) {
            float acc = be;
            #pragma unroll
            for (int k = 0; k < NFEAT; ++k)
                acc = fmaf(srow[g][k], sW[k * EMB + e], acc);
            float xv = lrelu(acc);
            x[(size_t)node * EMB + e] = xv;
            float macc = bm;
            #pragma unroll
            for (int k = 0; k < EMB; ++k)
                macc = fmaf(__shfl(xv, k, 32), sWm[k * EMB + e], macc);
            m[(size_t)node * EMB + e] = lrelu(macc);
        }
    }
}

// ---------------------------------------------------------------------------
// Bucketed CSR build (atomic-light counting sort by dst).
// Bucket b = dst >> 8 holds edges packed as (src<<8)|(dst&255).
// ---------------------------------------------------------------------------
__global__ __launch_bounds__(256) void k_bhist(
    const int* __restrict__ dst, int* __restrict__ bucket_cnt, int E, int nbuck)
{
    __shared__ int h[NBUCK_MAX];
    int t = threadIdx.x;
    for (int i = t; i < nbuck; i += 256) h[i] = 0;
    __syncthreads();
    for (int i = blockIdx.x * 256 + t; i < E; i += gridDim.x * 256)
        atomicAdd(&h[dst[i] >> 8], 1);
    __syncthreads();
    for (int i = t; i < nbuck; i += 256)
        if (h[i]) atomicAdd(&bucket_cnt[i], h[i]);
}

__global__ __launch_bounds__(512) void k_bscan(
    const int* __restrict__ bucket_cnt, int* __restrict__ bucket_base,
    int* __restrict__ bucket_cur, int nbuck)
{
    __shared__ int s[NBUCK_MAX];
    int t = threadIdx.x;
    int c = (t < nbuck) ? ((bucket_cnt[t] + 15) & ~15) : 0;   // 16-align each region
    s[t] = c;
    __syncthreads();
    for (int off = 1; off < NBUCK_MAX; off <<= 1) {
        int add = (t >= off) ? s[t - off] : 0;
        __syncthreads();
        s[t] += add;
        __syncthreads();
    }
    if (t < nbuck) {
        int base = s[t] - c;   // exclusive
        bucket_base[t] = base;
        bucket_cur[t] = base;
    }
}

__global__ __launch_bounds__(256) void k_bfill(
    const int* __restrict__ src, const int* __restrict__ dst,
    int* __restrict__ bucket_cur, unsigned int* __restrict__ csrp, int E)
{
    __shared__ int scnt[NBUCK_MAX];
    __shared__ int gbase[NBUCK_MAX];
    int t = threadIdx.x;
    for (int i = t; i < NBUCK_MAX; i += 256) scnt[i] = 0;
    __syncthreads();

    unsigned int vals[16];
    int br[16];
    int base = blockIdx.x * FILL_TILE;
    #pragma unroll
    for (int k = 0; k < 16; ++k) {
        int e = base + k * 256 + t;
        if (e < E) {
            int d = dst[e];
            int s = src[e];
            int b = d >> 8;
            int r = atomicAdd(&scnt[b], 1);          // LDS atomic: tile-local rank
            vals[k] = ((unsigned int)s << 8) | (unsigned int)(d & 255);
            br[k] = (b << 13) | r;                    // r < 4096 fits 13 bits
        } else br[k] = -1;
    }
    __syncthreads();
    for (int i = t; i < NBUCK_MAX; i += 256) {
        int c = scnt[i];
        gbase[i] = c ? atomicAdd(&bucket_cur[i], c) : 0;  // one global atomic/bucket/tile
    }
    __syncthreads();
    #pragma unroll
    for (int k = 0; k < 16; ++k) {
        if (br[k] >= 0) {
            int b = br[k] >> 13;
            int r = br[k] & 8191;
            csrp[gbase[b] + r] = vals[k];
        }
    }
}

// One block per bucket: sort bucket's edges by dst_local fully in LDS,
// emit deg/row for its 256 nodes, write back sorted src list IN PLACE.
__global__ __launch_bounds__(256) void k_csrfin(
    unsigned int* __restrict__ csrp, const int* __restrict__ bucket_base,
    const int* __restrict__ bucket_cnt, int* __restrict__ deg,
    int* __restrict__ row, int n)
{
    __shared__ int lh[RANGE], lb[RANGE], lc[RANGE];
    __shared__ int ssrc[FIN_CAP];
    int bk = blockIdx.x;
    int t = threadIdx.x;
    int base = bucket_base[bk];
    int cnt = bucket_cnt[bk];
    if (cnt > FIN_CAP) cnt = FIN_CAP;   // safety clamp (never hit for uniform graphs)
    int node0 = bk * RANGE;

    lh[t] = 0;
    __syncthreads();
    for (int i = t; i < cnt; i += 256)
        atomicAdd(&lh[csrp[base + i] & 255], 1);
    __syncthreads();
    // exclusive scan of lh -> lb
    lb[t] = lh[t];
    __syncthreads();
    for (int off = 1; off < RANGE; off <<= 1) {
        int add = (t >= off) ? lb[t - off] : 0;
        __syncthreads();
        lb[t] += add;
        __syncthreads();
    }
    lb[t] -= lh[t];
    __syncthreads();
    int node = node0 + t;
    if (node < n) {
        deg[node] = lh[t];
        row[node] = base + lb[t];
    }
    lc[t] = lb[t];
    __syncthreads();
    for (int i = t; i < cnt; i += 256) {
        unsigned int v = csrp[base + i];
        int dl = v & 255;
        int p = atomicAdd(&lc[dl], 1);
        ssrc[p] = (int)(v >> 8);
    }
    __syncthreads();
    for (int i = t; i < cnt; i += 256)
        csrp[base + i] = (unsigned int)ssrc[i];     // now a plain src list, dst-sorted
}

// ---------------------------------------------------------------------------
// Fused MP iteration: agg (CSR gather, 8 rows in flight) + update + next msg
// (+ colsum on the last iteration). Ping-pong m buffers.
// ---------------------------------------------------------------------------
__global__ __launch_bounds__(256) void k_mp(
    const float* __restrict__ m_in, float* __restrict__ m_out,
    float* __restrict__ x,
    const int* __restrict__ row_start, const int* __restrict__ deg,
    const int* __restrict__ csr_src,
    const float* __restrict__ Wupd, const float* __restrict__ bupd,
    const float* __restrict__ Wmsg, const float* __restrict__ bmsg,
    float* __restrict__ sums, int n, int do_msg, int do_colsum)
{
    __shared__ float sW[2 * EMB * EMB];
    __shared__ float sWm[EMB * EMB];
    __shared__ float red[8][EMB];
    int t = threadIdx.x;
    for (int i = t; i < 2 * EMB * EMB; i += 256) sW[i] = Wupd[i];
    for (int i = t; i < EMB * EMB; i += 256) sWm[i] = Wmsg[i];
    __syncthreads();

    int g = t >> 5;
    int e = t & 31;
    float bu = bupd[e];
    float bm = bmsg[e];
    float colacc = 0.f;
    int groups = gridDim.x * 8;
    for (int node = blockIdx.x * 8 + g; node < n; node += groups) {
        int s = row_start[node];
        int d = deg[node];
        float acc = 0.f;
        int j = 0;
        for (; j + 8 <= d; j += 8) {           // 8 independent 128B gathers in flight
            int i0 = csr_src[s + j + 0];
            int i1 = csr_src[s + j + 1];
            int i2 = csr_src[s + j + 2];
            int i3 = csr_src[s + j + 3];
            int i4 = csr_src[s + j + 4];
            int i5 = csr_src[s + j + 5];
            int i6 = csr_src[s + j + 6];
            int i7 = csr_src[s + j + 7];
            float a0 = m_in[(size_t)i0 * EMB + e];
            float a1 = m_in[(size_t)i1 * EMB + e];
            float a2 = m_in[(size_t)i2 * EMB + e];
            float a3 = m_in[(size_t)i3 * EMB + e];
            float a4 = m_in[(size_t)i4 * EMB + e];
            float a5 = m_in[(size_t)i5 * EMB + e];
            float a6 = m_in[(size_t)i6 * EMB + e];
            float a7 = m_in[(size_t)i7 * EMB + e];
            acc += ((a0 + a1) + (a2 + a3)) + ((a4 + a5) + (a6 + a7));
        }
        for (; j < d; ++j)
            acc += m_in[(size_t)csr_src[s + j] * EMB + e];

        float xv = x[(size_t)node * EMB + e];
        float u = bu;
        #pragma unroll
        for (int k = 0; k < EMB; ++k)
            u = fmaf(__shfl(xv, k, 32), sW[k * EMB + e], u);
        #pragma unroll
        for (int k = 0; k < EMB; ++k)
            u = fmaf(__shfl(acc, k, 32), sW[(EMB + k) * EMB + e], u);
        float xn = lrelu(u);
        x[(size_t)node * EMB + e] = xn;
        if (do_msg) {
            float macc = bm;
            #pragma unroll
            for (int k = 0; k < EMB; ++k)
                macc = fmaf(__shfl(xn, k, 32), sWm[k * EMB + e], macc);
            m_out[(size_t)node * EMB + e] = lrelu(macc);
        }
        if (do_colsum) colacc += xn;
    }
    if (do_colsum) {
        red[g][e] = colacc;
        __syncthreads();
        if (t < EMB) {
            float s2 = 0.f;
            #pragma unroll
            for (int gg = 0; gg < 8; ++gg) s2 += red[gg][t];
            atomicAdd(&sums[t], s2);
        }
    }
}

// ---------------------------------------------------------------------------
// Head: value = mean(x) @ W_val + b_val; probs = softmax(x[act] @ W_pol + b_pol)
// ---------------------------------------------------------------------------
__global__ __launch_bounds__(1024) void k_head(
    const float* __restrict__ x, const int* __restrict__ act,
    const float* __restrict__ Wval, const float* __restrict__ bval,
    const float* __restrict__ Wpol, const float* __restrict__ bpol,
    const float* __restrict__ sums, float* __restrict__ out, int n, int A)
{
    __shared__ float sred[64];
    int t = threadIdx.x;
    int w = t >> 6;
    int lane = t & 63;
    int nwaves = (blockDim.x + 63) >> 6;

    float logit = -INFINITY;
    if (t < A) {
        int node = act[t];
        float acc = bpol[0];
        #pragma unroll
        for (int k = 0; k < EMB; ++k)
            acc = fmaf(x[(size_t)node * EMB + k], Wpol[k], acc);
        logit = acc;
    }
    float wm = logit;
    for (int off = 32; off; off >>= 1) wm = fmaxf(wm, __shfl_xor(wm, off, 64));
    if (lane == 0) sred[w] = wm;
    __syncthreads();
    if (t == 0) {
        float mm = -INFINITY;
        for (int i = 0; i < nwaves; ++i) mm = fmaxf(mm, sred[i]);
        sred[32] = mm;
    }
    __syncthreads();
    float bmax = sred[32];
    float ex = (t < A) ? __expf(logit - bmax) : 0.f;
    float ws = ex;
    for (int off = 32; off; off >>= 1) ws += __shfl_xor(ws, off, 64);
    if (lane == 0) sred[w] = ws;
    __syncthreads();
    if (t == 0) {
        float ss = 0.f;
        for (int i = 0; i < nwaves; ++i) ss += sred[i];
        sred[33] = ss;
        float val = bval[0];
        float inv_n = 1.f / (float)n;
        #pragma unroll
        for (int k = 0; k < EMB; ++k) val = fmaf(sums[k] * inv_n, Wval[k], val);
        out[0] = val;
    }
    __syncthreads();
    float tot = sred[33];
    if (t < A) out[1 + t] = ex / tot;
}

// ---------------------------------------------------------------------------
extern "C" void kernel_launch(void* const* d_in, const int* in_sizes, int n_in,
                              void* d_out, int out_size, void* d_ws, size_t ws_size,
                              hipStream_t stream)
{
    const float* nf   = (const float*)d_in[0];
    const int*   ei   = (const int*)d_in[1];
    const int*   act  = (const int*)d_in[2];
    const float* Wemb = (const float*)d_in[3];
    const float* bemb = (const float*)d_in[4];
    const float* Wmsg = (const float*)d_in[5];
    const float* bmsg = (const float*)d_in[6];
    const float* Wupd = (const float*)d_in[7];
    const float* bupd = (const float*)d_in[8];
    const float* Wval = (const float*)d_in[9];
    const float* bval = (const float*)d_in[10];
    const float* Wpol = (const float*)d_in[11];
    const float* bpol = (const float*)d_in[12];

    int n = in_sizes[0] / NFEAT;
    int E = in_sizes[1] / 2;
    int A = in_sizes[2];
    const int* src = ei;
    const int* dst = ei + E;
    int nbuck = (n + RANGE - 1) / RANGE;          // 391 for n=100000

    char* w = (char*)d_ws;
    auto alloc = [&](size_t bytes) -> void* {
        void* p = (void*)w;
        w += (bytes + 255) & ~(size_t)255;
        return p;
    };
    float* x    = (float*)alloc((size_t)n * EMB * 4);
    float* mA   = (float*)alloc((size_t)n * EMB * 4);
    float* mB   = (float*)alloc((size_t)n * EMB * 4);
    int*   deg  = (int*)alloc((size_t)n * 4);
    int*   row  = (int*)alloc((size_t)n * 4);
    int*   bucket_cnt  = (int*)alloc((size_t)nbuck * 4);
    int*   bucket_base = (int*)alloc((size_t)nbuck * 4);
    int*   bucket_cur  = (int*)alloc((size_t)nbuck * 4);
    unsigned int* csrp = (unsigned int*)alloc(((size_t)E + (size_t)nbuck * 16) * 4);
    float* sums = (float*)alloc(EMB * 4);

    hipMemsetAsync(bucket_cnt, 0, (size_t)nbuck * 4, stream);
    hipMemsetAsync(sums, 0, EMB * 4, stream);

    const int NB = 2048;

    // embed (+ first message pass)
    k_embed<<<NB, 256, 0, stream>>>(nf, Wemb, bemb, Wmsg, bmsg, x, mA, n);

    // atomic-light CSR build (counting sort by dst)
    k_bhist<<<256, 256, 0, stream>>>(dst, bucket_cnt, E, nbuck);
    k_bscan<<<1, NBUCK_MAX, 0, stream>>>(bucket_cnt, bucket_base, bucket_cur, nbuck);
    int nfill = (E + FILL_TILE - 1) / FILL_TILE;
    k_bfill<<<nfill, 256, 0, stream>>>(src, dst, bucket_cur, csrp, E);
    k_csrfin<<<nbuck, 256, 0, stream>>>(csrp, bucket_base, bucket_cnt, deg, row, n);

    // 5 fused MP iterations (ping-pong message buffers)
    float* mi = mA;
    float* mo = mB;
    for (int it = 0; it < 5; ++it) {
        int last = (it == 4);
        k_mp<<<NB, 256, 0, stream>>>(mi, mo, x, row, deg, (const int*)csrp,
                                     Wupd, bupd, Wmsg, bmsg,
                                     sums, n, last ? 0 : 1, last ? 1 : 0);
        float* tmp = mi; mi = mo; mo = tmp;
    }

    k_head<<<1, 1024, 0, stream>>>(x, act, Wval, bval, Wpol, bpol, sums,
                                   (float*)d_out, n, A);
}